// Round 1
// 8998.935 us; speedup vs baseline: 2.5061x; 2.5061x over previous
//
#include <hip/hip_runtime.h>
#include <math.h>

#define TT 1024
#define DD 768
#define HH 12
#define HDD 64
#define LL 6
#define DFF 3072
#define VV 32000

// ---------------- reductions (wave = 64 on gfx950) ----------------
__device__ __forceinline__ float wave_sum(float v) {
#pragma unroll
  for (int o = 32; o > 0; o >>= 1) v += __shfl_down(v, o, 64);
  return v;
}
// block of 256 threads = 4 waves. buf must hold >=4 floats.
__device__ __forceinline__ float block_sum256(float v, float* buf) {
  v = wave_sum(v);
  int lane = threadIdx.x & 63, w = threadIdx.x >> 6;
  if (lane == 0) buf[w] = v;
  __syncthreads();
  float r = buf[0] + buf[1] + buf[2] + buf[3];
  __syncthreads();
  return r;
}

// ---------------- embedding: x[r,:] = tok_emb[idx[r],:] + pos_emb[r%T,:] ----
__global__ __launch_bounds__(256) void embed_kernel(const int* __restrict__ idx,
    const float* __restrict__ tok, const float* __restrict__ pos,
    float* __restrict__ x) {
  int r = blockIdx.x;          // 0..B*T-1, b-major
  int t = r & (TT - 1);
  int tokid = idx[r];
  const float* tp = tok + (size_t)tokid * DD;
  const float* pp = pos + (size_t)t * DD;
  float* xp = x + (size_t)r * DD;
#pragma unroll
  for (int i = 0; i < 3; ++i) {
    int c = threadIdx.x + i * 256;
    xp[c] = tp[c] + pp[c];
  }
}

// ---------------- LayerNorm: one block per row, D=768 -----------------------
__global__ __launch_bounds__(256) void ln_kernel(const float* __restrict__ x,
    const float* __restrict__ g, const float* __restrict__ b,
    float* __restrict__ y) {
  __shared__ float buf[4];
  int r = blockIdx.x;
  const float* xp = x + (size_t)r * DD;
  float vals[3];
  float s = 0.f;
#pragma unroll
  for (int i = 0; i < 3; ++i) { vals[i] = xp[threadIdx.x + i * 256]; s += vals[i]; }
  float mu = block_sum256(s, buf) * (1.f / DD);
  float vs = 0.f;
#pragma unroll
  for (int i = 0; i < 3; ++i) { float d = vals[i] - mu; vs += d * d; }
  float var = block_sum256(vs, buf) * (1.f / DD);
  float inv = rsqrtf(var + 1e-5f);
  float* yp = y + (size_t)r * DD;
#pragma unroll
  for (int i = 0; i < 3; ++i) {
    int c = threadIdx.x + i * 256;
    yp[c] = (vals[i] - mu) * inv * g[c] + b[c];
  }
}

// ---------------- tiled fp32 GEMM 64x64: C = [res +] act(A@B + bias) --------
template<bool GELU, bool RES>
__global__ __launch_bounds__(256) void gemm_kernel(const float* __restrict__ A,
    const float* __restrict__ B, const float* __restrict__ bias,
    const float* __restrict__ res, float* __restrict__ C, int N, int K) {
  constexpr int BM = 64, BN = 64, BK = 16;
  __shared__ float As[BK][BM + 1];
  __shared__ float Bs[BK][BN];
  int tid = threadIdx.x;
  int tx = tid & 15, ty = tid >> 4;
  int row0 = blockIdx.y * BM;
  int col0 = blockIdx.x * BN;
  float acc[4][4] = {};
  int am = tid >> 2;
  int ak = (tid & 3) << 2;
  int bk = tid >> 4;
  int bn = (tid & 15) << 2;
  for (int k0 = 0; k0 < K; k0 += BK) {
    float4 av = *(const float4*)(A + (size_t)(row0 + am) * K + k0 + ak);
    As[ak + 0][am] = av.x; As[ak + 1][am] = av.y;
    As[ak + 2][am] = av.z; As[ak + 3][am] = av.w;
    float4 bv = *(const float4*)(B + (size_t)(k0 + bk) * N + col0 + bn);
    *(float4*)&Bs[bk][bn] = bv;
    __syncthreads();
#pragma unroll
    for (int kk = 0; kk < BK; ++kk) {
      float a[4], b[4];
#pragma unroll
      for (int i = 0; i < 4; ++i) a[i] = As[kk][ty * 4 + i];
#pragma unroll
      for (int j = 0; j < 4; ++j) b[j] = Bs[kk][tx * 4 + j];
#pragma unroll
      for (int i = 0; i < 4; ++i)
#pragma unroll
        for (int j = 0; j < 4; ++j)
          acc[i][j] = fmaf(a[i], b[j], acc[i][j]);
    }
    __syncthreads();
  }
#pragma unroll
  for (int i = 0; i < 4; ++i) {
    int r = row0 + ty * 4 + i;
#pragma unroll
    for (int j = 0; j < 4; ++j) {
      int c = col0 + tx * 4 + j;
      float v = acc[i][j];
      if (bias) v += bias[c];
      if (GELU) v = 0.5f * v * (1.f + erff(v * 0.70710678118654752f));
      if (RES) v += res[(size_t)r * N + c];
      C[(size_t)r * N + c] = v;
    }
  }
}

// ---------------- tiled fp32 GEMM 128x128: for big-N GEMMs (FF1, head) ------
// 256 threads, 8x8 micro-tile split into 4 quadrants offset by 64 (2-way max
// LDS bank aliasing on all b128 reads).
template<bool GELU, bool RES>
__global__ __launch_bounds__(256) void gemm128_kernel(const float* __restrict__ A,
    const float* __restrict__ B, const float* __restrict__ bias,
    const float* __restrict__ res, float* __restrict__ C, int N, int K) {
  constexpr int BM = 128, BN = 128, BK = 16;
  __shared__ float As[BK][BM + 4];   // [k][m]
  __shared__ float Bs[BK][BN + 4];   // [k][n]
  int tid = threadIdx.x;
  int tx = tid & 15, ty = tid >> 4;
  int row0 = blockIdx.y * BM, col0 = blockIdx.x * BN;
  float acc[8][8] = {};
  int ar = tid >> 1, ak = (tid & 1) << 3;        // A: 128 rows x 16k, 8 k/thread
  int bk = tid >> 4, bn = (tid & 15) << 3;       // B: 16 rows x 128n, 8 n/thread
  for (int k0 = 0; k0 < K; k0 += BK) {
    const float* ap = A + (size_t)(row0 + ar) * K + k0 + ak;
    float4 a0 = *(const float4*)(ap);
    float4 a1 = *(const float4*)(ap + 4);
    const float* bp = B + (size_t)(k0 + bk) * N + col0 + bn;
    float4 b0 = *(const float4*)(bp);
    float4 b1 = *(const float4*)(bp + 4);
    __syncthreads();                  // prev compute done before overwrite
    As[ak + 0][ar] = a0.x; As[ak + 1][ar] = a0.y;
    As[ak + 2][ar] = a0.z; As[ak + 3][ar] = a0.w;
    As[ak + 4][ar] = a1.x; As[ak + 5][ar] = a1.y;
    As[ak + 6][ar] = a1.z; As[ak + 7][ar] = a1.w;
    *(float4*)&Bs[bk][bn] = b0;
    *(float4*)&Bs[bk][bn + 4] = b1;
    __syncthreads();
#pragma unroll
    for (int kk = 0; kk < BK; ++kk) {
      float4 aLo = *(const float4*)&As[kk][ty * 4];
      float4 aHi = *(const float4*)&As[kk][64 + ty * 4];
      float4 bLo = *(const float4*)&Bs[kk][tx * 4];
      float4 bHi = *(const float4*)&Bs[kk][64 + tx * 4];
      float av[8] = {aLo.x, aLo.y, aLo.z, aLo.w, aHi.x, aHi.y, aHi.z, aHi.w};
      float bv[8] = {bLo.x, bLo.y, bLo.z, bLo.w, bHi.x, bHi.y, bHi.z, bHi.w};
#pragma unroll
      for (int i = 0; i < 8; ++i)
#pragma unroll
        for (int j = 0; j < 8; ++j)
          acc[i][j] = fmaf(av[i], bv[j], acc[i][j]);
    }
  }
#pragma unroll
  for (int ih = 0; ih < 2; ++ih)
#pragma unroll
    for (int i = 0; i < 4; ++i) {
      int r = row0 + ih * 64 + ty * 4 + i;
#pragma unroll
      for (int jh = 0; jh < 2; ++jh) {
        int c = col0 + jh * 64 + tx * 4;
        float v[4];
#pragma unroll
        for (int j = 0; j < 4; ++j) v[j] = acc[ih * 4 + i][jh * 4 + j];
        if (bias) {
          float4 bb = *(const float4*)(bias + c);
          v[0] += bb.x; v[1] += bb.y; v[2] += bb.z; v[3] += bb.w;
        }
        if (GELU) {
#pragma unroll
          for (int j = 0; j < 4; ++j)
            v[j] = 0.5f * v[j] * (1.f + erff(v[j] * 0.70710678118654752f));
        }
        if (RES) {
          float4 rr = *(const float4*)(res + (size_t)r * N + c);
          v[0] += rr.x; v[1] += rr.y; v[2] += rr.z; v[3] += rr.w;
        }
        float4 out4 = {v[0], v[1], v[2], v[3]};
        *(float4*)(C + (size_t)r * N + c) = out4;
      }
    }
}

// ---------------- flash attention: one block per (b, h, 64-row q-tile) ------
// K/V staged in LDS in 64x64 tiles; online softmax; P*V in registers.
// Qt/KP hold transposed (d-major) operands so inner reads are b128.
// KP is K^T during S-phase, then reused as P (q-major) for the PV phase.
__global__ __launch_bounds__(256) void fattn_kernel(const float* __restrict__ q,
    const float* __restrict__ k, const float* __restrict__ v,
    float* __restrict__ o) {
  constexpr int PD = 68;                 // pad: 16B-aligned rows, 2-way banks
  __shared__ float Qt[HDD][PD];          // Q^T [d][qrow], pre-scaled
  __shared__ float KP[HDD][PD];          // K^T [d][krow]  ->  P [qrow][k]
  __shared__ float Vs[HDD][PD];          // V   [krow][d]
  // pair big/small tiles in dispatch order: {15,0,14,1,...} for tail balance
  int xb = blockIdx.x;
  int qt = (xb & 1) ? (xb >> 1) : (15 - (xb >> 1));
  int h = blockIdx.y, b = blockIdx.z;
  int tid = threadIdx.x;
  int tx = tid & 15, ty = tid >> 4;
  int lr = tid >> 2;                     // token row in tile 0..63
  int lc = (tid & 3) << 4;               // col chunk base 0,16,32,48
  {                                      // load + transpose + scale Q
    const float* qp = q + ((size_t)(b * TT + qt * 64 + lr)) * DD + h * HDD + lc;
#pragma unroll
    for (int i0 = 0; i0 < 4; ++i0) {
      float4 t = *(const float4*)(qp + i0 * 4);
      Qt[lc + i0 * 4 + 0][lr] = t.x * 0.125f;
      Qt[lc + i0 * 4 + 1][lr] = t.y * 0.125f;
      Qt[lc + i0 * 4 + 2][lr] = t.z * 0.125f;
      Qt[lc + i0 * 4 + 3][lr] = t.w * 0.125f;
    }
  }
  float m_i[4], l_i[4], oacc[4][4];
#pragma unroll
  for (int i = 0; i < 4; ++i) {
    m_i[i] = -3.0e38f; l_i[i] = 0.f;
#pragma unroll
    for (int j = 0; j < 4; ++j) oacc[i][j] = 0.f;
  }
  for (int kt = 0; kt <= qt; ++kt) {
    const float* kp = k + ((size_t)(b * TT + kt * 64 + lr)) * DD + h * HDD + lc;
    const float* vp = v + ((size_t)(b * TT + kt * 64 + lr)) * DD + h * HDD + lc;
    float4 kv[4], vv[4];
#pragma unroll
    for (int i0 = 0; i0 < 4; ++i0) {
      kv[i0] = *(const float4*)(kp + i0 * 4);
      vv[i0] = *(const float4*)(vp + i0 * 4);
    }
    __syncthreads();                     // prior PV reads done
#pragma unroll
    for (int i0 = 0; i0 < 4; ++i0) {     // K transposed, V natural
      KP[lc + i0 * 4 + 0][lr] = kv[i0].x;
      KP[lc + i0 * 4 + 1][lr] = kv[i0].y;
      KP[lc + i0 * 4 + 2][lr] = kv[i0].z;
      KP[lc + i0 * 4 + 3][lr] = kv[i0].w;
      *(float4*)&Vs[lr][lc + i0 * 4] = vv[i0];
    }
    __syncthreads();
    // S[q=4ty+i][k=4tx+j] = (Q*scale) . K
    float s[4][4] = {};
#pragma unroll 8
    for (int d = 0; d < HDD; ++d) {
      float4 a4 = *(const float4*)&Qt[d][ty * 4];
      float4 b4 = *(const float4*)&KP[d][tx * 4];
      float av[4] = {a4.x, a4.y, a4.z, a4.w};
      float bv[4] = {b4.x, b4.y, b4.z, b4.w};
#pragma unroll
      for (int i = 0; i < 4; ++i)
#pragma unroll
        for (int j = 0; j < 4; ++j) s[i][j] = fmaf(av[i], bv[j], s[i][j]);
    }
    __syncthreads();                     // all K^T reads done; KP becomes P
    if (kt == qt) {                      // causal mask, diagonal tile only
#pragma unroll
      for (int i = 0; i < 4; ++i)
#pragma unroll
        for (int j = 0; j < 4; ++j)
          if (tx * 4 + j > ty * 4 + i) s[i][j] = -3.0e38f;
    }
#pragma unroll
    for (int i = 0; i < 4; ++i) {        // online softmax, row across 16 tx lanes
      float mx = fmaxf(fmaxf(s[i][0], s[i][1]), fmaxf(s[i][2], s[i][3]));
      mx = fmaxf(mx, __shfl_xor(mx, 1, 64));
      mx = fmaxf(mx, __shfl_xor(mx, 2, 64));
      mx = fmaxf(mx, __shfl_xor(mx, 4, 64));
      mx = fmaxf(mx, __shfl_xor(mx, 8, 64));
      float mnew = fmaxf(m_i[i], mx);
      float corr = __expf(m_i[i] - mnew);
      float ps = 0.f;
#pragma unroll
      for (int j = 0; j < 4; ++j) { s[i][j] = __expf(s[i][j] - mnew); ps += s[i][j]; }
      ps += __shfl_xor(ps, 1, 64);
      ps += __shfl_xor(ps, 2, 64);
      ps += __shfl_xor(ps, 4, 64);
      ps += __shfl_xor(ps, 8, 64);
      l_i[i] = l_i[i] * corr + ps;
      m_i[i] = mnew;
#pragma unroll
      for (int j = 0; j < 4; ++j) oacc[i][j] *= corr;
      float4 p4 = {s[i][0], s[i][1], s[i][2], s[i][3]};
      *(float4*)&KP[ty * 4 + i][tx * 4] = p4;   // P[q][k], b128 store
    }
    __syncthreads();
    // O[q][d=4tx+j] += sum_k P[q][k] * V[k][d]
#pragma unroll 2
    for (int k4 = 0; k4 < 64; k4 += 4) {
      float p[4][4];
#pragma unroll
      for (int i = 0; i < 4; ++i)
        *(float4*)&p[i][0] = *(const float4*)&KP[ty * 4 + i][k4];
#pragma unroll
      for (int kk = 0; kk < 4; ++kk) {
        float4 b4 = *(const float4*)&Vs[k4 + kk][tx * 4];
        float bv[4] = {b4.x, b4.y, b4.z, b4.w};
#pragma unroll
        for (int i = 0; i < 4; ++i)
#pragma unroll
          for (int j = 0; j < 4; ++j)
            oacc[i][j] = fmaf(p[i][kk], bv[j], oacc[i][j]);
      }
    }
  }
#pragma unroll
  for (int i = 0; i < 4; ++i) {
    float inv = 1.f / l_i[i];
    float4 r = {oacc[i][0] * inv, oacc[i][1] * inv,
                oacc[i][2] * inv, oacc[i][3] * inv};
    *(float4*)(o + ((size_t)(b * TT + qt * 64 + ty * 4 + i)) * DD
               + h * HDD + tx * 4) = r;
  }
}

// ---------------- orchestration ---------------------------------------------
extern "C" void kernel_launch(void* const* d_in, const int* in_sizes, int n_in,
                              void* d_out, int out_size, void* d_ws, size_t ws_size,
                              hipStream_t stream) {
  const int Bc = 4, M = Bc * TT;       // 4096 rows
  const int* idx   = (const int*)d_in[0];
  const float* tok = (const float*)d_in[1];
  const float* pos = (const float*)d_in[2];
  const float* Wq  = (const float*)d_in[3];
  const float* Wk  = (const float*)d_in[4];
  const float* Wv  = (const float*)d_in[5];
  const float* Wo  = (const float*)d_in[6];
  const float* bo  = (const float*)d_in[7];
  const float* W1  = (const float*)d_in[8];
  const float* b1  = (const float*)d_in[9];
  const float* W2  = (const float*)d_in[10];
  const float* b2  = (const float*)d_in[11];
  const float* ln1g = (const float*)d_in[12];
  const float* ln1b = (const float*)d_in[13];
  const float* ln2g = (const float*)d_in[14];
  const float* ln2b = (const float*)d_in[15];
  const float* lnfg = (const float*)d_in[16];
  const float* lnfb = (const float*)d_in[17];
  const float* hW  = (const float*)d_in[18];
  const float* hb  = (const float*)d_in[19];
  float* out = (float*)d_out;

  // workspace layout (floats): x, h, then q|k|v|o (q..o span reused as the
  // [M,DFF] FF intermediate — 4*D == DFF so it fits exactly).
  float* x  = (float*)d_ws;
  float* h  = x  + (size_t)M * DD;
  float* qb = h  + (size_t)M * DD;
  float* kb = qb + (size_t)M * DD;
  float* vb = kb + (size_t)M * DD;
  float* ob = vb + (size_t)M * DD;
  float* f1 = qb;                      // [M, DFF] alias over q|k|v|o

  dim3 blk(256);
  dim3 gD(DD / 64, M / 64);            // 64-tile grids (N=768)
  dim3 gF128(DFF / 128, M / 128);      // FF1 on 128-tiles
  dim3 gV128(VV / 128, M / 128);       // head on 128-tiles

  embed_kernel<<<M, blk, 0, stream>>>(idx, tok, pos, x);
  for (int l = 0; l < LL; ++l) {
    ln_kernel<<<M, blk, 0, stream>>>(x, ln1g + l * DD, ln1b + l * DD, h);
    gemm_kernel<false, false><<<gD, blk, 0, stream>>>(h, Wq + (size_t)l * DD * DD, nullptr, nullptr, qb, DD, DD);
    gemm_kernel<false, false><<<gD, blk, 0, stream>>>(h, Wk + (size_t)l * DD * DD, nullptr, nullptr, kb, DD, DD);
    gemm_kernel<false, false><<<gD, blk, 0, stream>>>(h, Wv + (size_t)l * DD * DD, nullptr, nullptr, vb, DD, DD);
    fattn_kernel<<<dim3(TT / 64, HH, Bc), blk, 0, stream>>>(qb, kb, vb, ob);
    gemm_kernel<false, true><<<gD, blk, 0, stream>>>(ob, Wo + (size_t)l * DD * DD, bo + l * DD, x, x, DD, DD);
    ln_kernel<<<M, blk, 0, stream>>>(x, ln2g + l * DD, ln2b + l * DD, h);
    gemm128_kernel<true, false><<<gF128, blk, 0, stream>>>(h, W1 + (size_t)l * DD * DFF, b1 + l * DFF, nullptr, f1, DFF, DD);
    gemm_kernel<false, true><<<gD, blk, 0, stream>>>(f1, W2 + (size_t)l * DFF * DD, b2 + l * DD, x, x, DD, DFF);
  }
  ln_kernel<<<M, blk, 0, stream>>>(x, lnfg, lnfb, h);
  gemm128_kernel<false, false><<<gV128, blk, 0, stream>>>(h, hW, hb, nullptr, out, VV, DD);
}

// Round 3
// 3407.187 us; speedup vs baseline: 6.6191x; 2.6412x over previous
//
#include <hip/hip_runtime.h>
#include <math.h>

#define TT 1024
#define DD 768
#define HH 12
#define HDD 64
#define LL 6
#define DFF 3072
#define VV 32000

using bf8v = __attribute__((ext_vector_type(8))) short;
using f4v  = __attribute__((ext_vector_type(4))) float;

// fp32 -> bf16 round-to-nearest-even
__device__ __forceinline__ uint f2bf(float f) {
  uint u = __float_as_uint(f);
  return (u + 0x7fffu + ((u >> 16) & 1u)) >> 16;
}
__device__ __forceinline__ uint pk2(float lo, float hi) {
  return f2bf(lo) | (f2bf(hi) << 16);
}
__device__ __forceinline__ float bf2f(ushort u) {
  return __uint_as_float((uint)u << 16);
}

// ---------------- reductions (wave = 64 on gfx950) ----------------
__device__ __forceinline__ float wave_sum(float v) {
#pragma unroll
  for (int o = 32; o > 0; o >>= 1) v += __shfl_down(v, o, 64);
  return v;
}
__device__ __forceinline__ float block_sum256(float v, float* buf) {
  v = wave_sum(v);
  int lane = threadIdx.x & 63, w = threadIdx.x >> 6;
  if (lane == 0) buf[w] = v;
  __syncthreads();
  float r = buf[0] + buf[1] + buf[2] + buf[3];
  __syncthreads();
  return r;
}

// ---------------- embedding -------------------------------------------------
__global__ __launch_bounds__(256) void embed_kernel(const int* __restrict__ idx,
    const float* __restrict__ tok, const float* __restrict__ pos,
    float* __restrict__ x) {
  int r = blockIdx.x;
  int t = r & (TT - 1);
  int tokid = idx[r];
  const float* tp = tok + (size_t)tokid * DD;
  const float* pp = pos + (size_t)t * DD;
  float* xp = x + (size_t)r * DD;
#pragma unroll
  for (int i = 0; i < 3; ++i) {
    int c = threadIdx.x + i * 256;
    xp[c] = tp[c] + pp[c];
  }
}

// ---------------- LayerNorm: fp32 in, bf16 out ------------------------------
__global__ __launch_bounds__(256) void ln_kernel(const float* __restrict__ x,
    const float* __restrict__ g, const float* __restrict__ b,
    ushort* __restrict__ y) {
  __shared__ float buf[4];
  int r = blockIdx.x;
  const float* xp = x + (size_t)r * DD;
  float vals[3];
  float s = 0.f;
#pragma unroll
  for (int i = 0; i < 3; ++i) { vals[i] = xp[threadIdx.x + i * 256]; s += vals[i]; }
  float mu = block_sum256(s, buf) * (1.f / DD);
  float vs = 0.f;
#pragma unroll
  for (int i = 0; i < 3; ++i) { float d = vals[i] - mu; vs += d * d; }
  float var = block_sum256(vs, buf) * (1.f / DD);
  float inv = rsqrtf(var + 1e-5f);
  ushort* yp = y + (size_t)r * DD;
#pragma unroll
  for (int i = 0; i < 3; ++i) {
    int c = threadIdx.x + i * 256;
    yp[c] = (ushort)f2bf((vals[i] - mu) * inv * g[c] + b[c]);
  }
}

// ---------------- weight transpose + bf16 convert: out[n][k] = bf16(in[k][n])
__global__ __launch_bounds__(256) void wtrans_kernel(const float* __restrict__ in,
    ushort* __restrict__ out, int K, int N) {
  __shared__ float t[64][65];
  int n0 = blockIdx.x * 64, k0 = blockIdx.y * 64;
  int tid = threadIdx.x;
  int c4 = (tid & 15) * 4, rr = tid >> 4;
#pragma unroll
  for (int p = 0; p < 4; ++p) {
    float4 v = *(const float4*)(in + (size_t)(k0 + rr + p * 16) * N + n0 + c4);
    t[rr + p * 16][c4 + 0] = v.x; t[rr + p * 16][c4 + 1] = v.y;
    t[rr + p * 16][c4 + 2] = v.z; t[rr + p * 16][c4 + 3] = v.w;
  }
  __syncthreads();
#pragma unroll
  for (int p = 0; p < 4; ++p) {
    int n = rr + p * 16;
    uint2 w;
    w.x = pk2(t[c4 + 0][n], t[c4 + 1][n]);
    w.y = pk2(t[c4 + 2][n], t[c4 + 3][n]);
    *(uint2*)(out + (size_t)(n0 + n) * K + k0 + c4) = w;
  }
}

// ---------------- bf16 MFMA GEMM: C = [res +] act(A@B + bias) ---------------
// A [M,K] bf16 row-major; Bt [N,K] bf16 (pre-transposed).
// 128x128 tile, BK=32, 256 threads = 4 waves (2x2), 4x4 16x16 frags per wave.
// LDS row stride 40 ushorts (80B): 16B-aligned b128 frags, <=2-way conflicts.
template<bool GELU, bool RES, bool OUTBF>
__global__ __launch_bounds__(256) void gemm_mfma(const ushort* __restrict__ A,
    const ushort* __restrict__ Bt, const float* __restrict__ bias,
    const float* __restrict__ res, void* __restrict__ Cv,
    int N, int K, int ny) {
  constexpr int BM = 128, BK = 32, LDT = 40;
  __shared__ __align__(16) ushort As[BM * LDT];
  __shared__ __align__(16) ushort Bs[BM * LDT];
  int bid = blockIdx.x;
  int rB = bid % ny, cB = bid / ny;     // rows fastest: B-tile L2-hot
  int row0 = rB * BM, col0 = cB * BM;
  int tid = threadIdx.x;
  int lane = tid & 63, wid = tid >> 6;
  int wr = (wid >> 1) * 64, wc = (wid & 1) * 64;
  int fr = lane & 15, fg = lane >> 4;
  f4v acc[4][4];
#pragma unroll
  for (int i = 0; i < 4; ++i)
#pragma unroll
    for (int j = 0; j < 4; ++j) acc[i][j] = (f4v){0.f, 0.f, 0.f, 0.f};
  int sr = tid >> 1, sk = (tid & 1) << 4;     // staging: row, 16-elem k-half
  const ushort* aP = A  + (size_t)(row0 + sr) * K + sk;
  const ushort* bP = Bt + (size_t)(col0 + sr) * K + sk;
  ushort* asW = &As[sr * LDT + sk];
  ushort* bsW = &Bs[sr * LDT + sk];
  uint4 a0 = *(const uint4*)(aP), a1 = *(const uint4*)(aP + 8);
  uint4 b0 = *(const uint4*)(bP), b1 = *(const uint4*)(bP + 8);
  for (int k0 = 0;;) {
    __syncthreads();                          // frag reads of prev tile done
    *(uint4*)asW = a0; *(uint4*)(asW + 8) = a1;
    *(uint4*)bsW = b0; *(uint4*)(bsW + 8) = b1;
    __syncthreads();
    k0 += BK;
    if (k0 < K) {                             // prefetch next before compute
      a0 = *(const uint4*)(aP + k0);  a1 = *(const uint4*)(aP + k0 + 8);
      b0 = *(const uint4*)(bP + k0);  b1 = *(const uint4*)(bP + k0 + 8);
    }
    bf8v af[4], bf[4];
#pragma unroll
    for (int i = 0; i < 4; ++i)
      af[i] = *(const bf8v*)&As[(wr + i * 16 + fr) * LDT + fg * 8];
#pragma unroll
    for (int j = 0; j < 4; ++j)
      bf[j] = *(const bf8v*)&Bs[(wc + j * 16 + fr) * LDT + fg * 8];
#pragma unroll
    for (int i = 0; i < 4; ++i)
#pragma unroll
      for (int j = 0; j < 4; ++j)
        acc[i][j] = __builtin_amdgcn_mfma_f32_16x16x32_bf16(af[i], bf[j], acc[i][j], 0, 0, 0);
    if (k0 >= K) break;
  }
  // epilogue: C/D map col=lane&15, row=(lane>>4)*4+r  [HW-verified m89/m91]
#pragma unroll
  for (int j = 0; j < 4; ++j) {
    int cc = col0 + wc + j * 16 + fr;
    float bv = bias ? bias[cc] : 0.f;
#pragma unroll
    for (int i = 0; i < 4; ++i) {
#pragma unroll
      for (int r = 0; r < 4; ++r) {
        int rr2 = row0 + wr + i * 16 + fg * 4 + r;
        float v = acc[i][j][r] + bv;
        if (GELU) v = 0.5f * v * (1.f + erff(v * 0.70710678118654752f));
        if (RES) v += res[(size_t)rr2 * N + cc];
        if (OUTBF) ((ushort*)Cv)[(size_t)rr2 * N + cc] = (ushort)f2bf(v);
        else       ((float*)Cv)[(size_t)rr2 * N + cc] = v;
      }
    }
  }
}

// ---------------- flash attention: bf16 q/k/v in, bf16 o out, fp32 compute --
__global__ __launch_bounds__(256) void fattn_kernel(const ushort* __restrict__ q,
    const ushort* __restrict__ k, const ushort* __restrict__ v,
    ushort* __restrict__ o, int ld) {
  constexpr int PD = 68;
  __shared__ float Qt[HDD][PD];          // Q^T [d][qrow], pre-scaled
  __shared__ float KP[HDD][PD];          // K^T [d][krow] -> P [qrow][k]
  __shared__ float Vs[HDD][PD];          // V   [krow][d]
  int xb = blockIdx.x;
  int qt = (xb & 1) ? (xb >> 1) : (15 - (xb >> 1));
  int h = blockIdx.y, b = blockIdx.z;
  int tid = threadIdx.x;
  int tx = tid & 15, ty = tid >> 4;
  int lr = tid >> 2;                     // token row in tile 0..63
  int lc = (tid & 3) << 4;               // col chunk base 0,16,32,48
  {
    const ushort* qp = q + ((size_t)(b * TT + qt * 64 + lr)) * ld + h * HDD + lc;
    uint4 u0 = *(const uint4*)(qp), u1 = *(const uint4*)(qp + 8);
    const uint* uw = (const uint*)&u0;
#pragma unroll
    for (int i0 = 0; i0 < 4; ++i0) {
      Qt[lc + i0 * 2 + 0][lr] = bf2f((ushort)(uw[i0] & 0xffffu)) * 0.125f;
      Qt[lc + i0 * 2 + 1][lr] = bf2f((ushort)(uw[i0] >> 16)) * 0.125f;
    }
    const uint* uw1 = (const uint*)&u1;
#pragma unroll
    for (int i0 = 0; i0 < 4; ++i0) {
      Qt[lc + 8 + i0 * 2 + 0][lr] = bf2f((ushort)(uw1[i0] & 0xffffu)) * 0.125f;
      Qt[lc + 8 + i0 * 2 + 1][lr] = bf2f((ushort)(uw1[i0] >> 16)) * 0.125f;
    }
  }
  float m_i[4], l_i[4], oacc[4][4];
#pragma unroll
  for (int i = 0; i < 4; ++i) {
    m_i[i] = -3.0e38f; l_i[i] = 0.f;
#pragma unroll
    for (int j = 0; j < 4; ++j) oacc[i][j] = 0.f;
  }
  for (int kt = 0; kt <= qt; ++kt) {
    const ushort* kp = k + ((size_t)(b * TT + kt * 64 + lr)) * ld + h * HDD + lc;
    const ushort* vp = v + ((size_t)(b * TT + kt * 64 + lr)) * ld + h * HDD + lc;
    uint4 ku0 = *(const uint4*)(kp), ku1 = *(const uint4*)(kp + 8);
    uint4 vu0 = *(const uint4*)(vp), vu1 = *(const uint4*)(vp + 8);
    __syncthreads();                     // prior PV reads done
    {
      const uint* a = (const uint*)&ku0; const uint* c = (const uint*)&ku1;
#pragma unroll
      for (int i0 = 0; i0 < 4; ++i0) {
        KP[lc + i0 * 2 + 0][lr] = bf2f((ushort)(a[i0] & 0xffffu));
        KP[lc + i0 * 2 + 1][lr] = bf2f((ushort)(a[i0] >> 16));
        KP[lc + 8 + i0 * 2 + 0][lr] = bf2f((ushort)(c[i0] & 0xffffu));
        KP[lc + 8 + i0 * 2 + 1][lr] = bf2f((ushort)(c[i0] >> 16));
      }
      const uint* d0 = (const uint*)&vu0; const uint* d1 = (const uint*)&vu1;
      float4 w0 = {bf2f((ushort)(d0[0] & 0xffffu)), bf2f((ushort)(d0[0] >> 16)),
                   bf2f((ushort)(d0[1] & 0xffffu)), bf2f((ushort)(d0[1] >> 16))};
      float4 w1 = {bf2f((ushort)(d0[2] & 0xffffu)), bf2f((ushort)(d0[2] >> 16)),
                   bf2f((ushort)(d0[3] & 0xffffu)), bf2f((ushort)(d0[3] >> 16))};
      float4 w2 = {bf2f((ushort)(d1[0] & 0xffffu)), bf2f((ushort)(d1[0] >> 16)),
                   bf2f((ushort)(d1[1] & 0xffffu)), bf2f((ushort)(d1[1] >> 16))};
      float4 w3 = {bf2f((ushort)(d1[2] & 0xffffu)), bf2f((ushort)(d1[2] >> 16)),
                   bf2f((ushort)(d1[3] & 0xffffu)), bf2f((ushort)(d1[3] >> 16))};
      *(float4*)&Vs[lr][lc + 0]  = w0;
      *(float4*)&Vs[lr][lc + 4]  = w1;
      *(float4*)&Vs[lr][lc + 8]  = w2;
      *(float4*)&Vs[lr][lc + 12] = w3;
    }
    __syncthreads();
    float s[4][4] = {};
#pragma unroll 8
    for (int d = 0; d < HDD; ++d) {
      float4 a4 = *(const float4*)&Qt[d][ty * 4];
      float4 b4 = *(const float4*)&KP[d][tx * 4];
      float av[4] = {a4.x, a4.y, a4.z, a4.w};
      float bv[4] = {b4.x, b4.y, b4.z, b4.w};
#pragma unroll
      for (int i = 0; i < 4; ++i)
#pragma unroll
        for (int j = 0; j < 4; ++j) s[i][j] = fmaf(av[i], bv[j], s[i][j]);
    }
    __syncthreads();                     // K^T reads done; KP becomes P
    if (kt == qt) {
#pragma unroll
      for (int i = 0; i < 4; ++i)
#pragma unroll
        for (int j = 0; j < 4; ++j)
          if (tx * 4 + j > ty * 4 + i) s[i][j] = -3.0e38f;
    }
#pragma unroll
    for (int i = 0; i < 4; ++i) {        // online softmax across 16 tx lanes
      float mx = fmaxf(fmaxf(s[i][0], s[i][1]), fmaxf(s[i][2], s[i][3]));
      mx = fmaxf(mx, __shfl_xor(mx, 1, 64));
      mx = fmaxf(mx, __shfl_xor(mx, 2, 64));
      mx = fmaxf(mx, __shfl_xor(mx, 4, 64));
      mx = fmaxf(mx, __shfl_xor(mx, 8, 64));
      float mnew = fmaxf(m_i[i], mx);
      float corr = __expf(m_i[i] - mnew);
      float ps = 0.f;
#pragma unroll
      for (int j = 0; j < 4; ++j) { s[i][j] = __expf(s[i][j] - mnew); ps += s[i][j]; }
      ps += __shfl_xor(ps, 1, 64);
      ps += __shfl_xor(ps, 2, 64);
      ps += __shfl_xor(ps, 4, 64);
      ps += __shfl_xor(ps, 8, 64);
      l_i[i] = l_i[i] * corr + ps;
      m_i[i] = mnew;
#pragma unroll
      for (int j = 0; j < 4; ++j) oacc[i][j] *= corr;
      float4 p4 = {s[i][0], s[i][1], s[i][2], s[i][3]};
      *(float4*)&KP[ty * 4 + i][tx * 4] = p4;
    }
    __syncthreads();
#pragma unroll 2
    for (int k4 = 0; k4 < 64; k4 += 4) {
      float p[4][4];
#pragma unroll
      for (int i = 0; i < 4; ++i)
        *(float4*)&p[i][0] = *(const float4*)&KP[ty * 4 + i][k4];
#pragma unroll
      for (int kk = 0; kk < 4; ++kk) {
        float4 b4 = *(const float4*)&Vs[k4 + kk][tx * 4];
        float bv[4] = {b4.x, b4.y, b4.z, b4.w};
#pragma unroll
        for (int i = 0; i < 4; ++i)
#pragma unroll
          for (int j = 0; j < 4; ++j)
            oacc[i][j] = fmaf(p[i][kk], bv[j], oacc[i][j]);
      }
    }
  }
#pragma unroll
  for (int i = 0; i < 4; ++i) {
    float inv = 1.f / l_i[i];
    uint2 r;
    r.x = pk2(oacc[i][0] * inv, oacc[i][1] * inv);
    r.y = pk2(oacc[i][2] * inv, oacc[i][3] * inv);
    *(uint2*)(o + ((size_t)(b * TT + qt * 64 + ty * 4 + i)) * DD
              + h * HDD + tx * 4) = r;
  }
}

// ---------------- orchestration ---------------------------------------------
extern "C" void kernel_launch(void* const* d_in, const int* in_sizes, int n_in,
                              void* d_out, int out_size, void* d_ws, size_t ws_size,
                              hipStream_t stream) {
  const int Bc = 4, M = Bc * TT;       // 4096 rows
  const int* idx   = (const int*)d_in[0];
  const float* tok = (const float*)d_in[1];
  const float* pos = (const float*)d_in[2];
  const float* Wq  = (const float*)d_in[3];
  const float* Wk  = (const float*)d_in[4];
  const float* Wv  = (const float*)d_in[5];
  const float* Wo  = (const float*)d_in[6];
  const float* bo  = (const float*)d_in[7];
  const float* W1  = (const float*)d_in[8];
  const float* b1  = (const float*)d_in[9];
  const float* W2  = (const float*)d_in[10];
  const float* b2  = (const float*)d_in[11];
  const float* ln1g = (const float*)d_in[12];
  const float* ln1b = (const float*)d_in[13];
  const float* ln2g = (const float*)d_in[14];
  const float* ln2b = (const float*)d_in[15];
  const float* lnfg = (const float*)d_in[16];
  const float* lnfb = (const float*)d_in[17];
  const float* hW  = (const float*)d_in[18];
  const float* hb  = (const float*)d_in[19];
  float* out = (float*)d_out;

  // workspace (68.0 MB total, <= proven 75.5 MB footprint):
  //   x   fp32 [M][768]                      12.58 MB
  //   h   bf16 [M][768]                       6.29 MB
  //   R region (49.15 MB):
  //     qkv bf16 [M][2304]   (18.87)  | f1 bf16 [M][3072] aliases qkv+ob exact
  //     ob  bf16 [M][768]    ( 6.29)  | hWT bf16 [32000][768] aliases whole R
  //     Wt  bf16 weights     (14.16)
  float*  x   = (float*)d_ws;
  ushort* h   = (ushort*)(x + (size_t)M * DD);
  ushort* qkv = h + (size_t)M * DD;
  ushort* ob  = qkv + (size_t)M * 3 * DD;
  ushort* Wt  = ob + (size_t)M * DD;
  ushort* f1  = qkv;
  ushort* hWT = qkv;

  const size_t SQ = (size_t)DD * DD;               // 589824
  ushort* WqT = Wt;                                // [2304][768] (q|k|v)
  ushort* WoT = Wt + 3 * SQ;                       // [768][768]
  ushort* W1T = Wt + 4 * SQ;                       // [3072][768]
  ushort* W2T = W1T + (size_t)DD * DFF;            // [768][3072]

  dim3 blk(256);
  embed_kernel<<<M, blk, 0, stream>>>(idx, tok, pos, x);
  for (int l = 0; l < LL; ++l) {
    wtrans_kernel<<<dim3(12, 12), blk, 0, stream>>>(Wq + l * SQ, WqT + 0 * SQ, DD, DD);
    wtrans_kernel<<<dim3(12, 12), blk, 0, stream>>>(Wk + l * SQ, WqT + 1 * SQ, DD, DD);
    wtrans_kernel<<<dim3(12, 12), blk, 0, stream>>>(Wv + l * SQ, WqT + 2 * SQ, DD, DD);
    wtrans_kernel<<<dim3(12, 12), blk, 0, stream>>>(Wo + l * SQ, WoT, DD, DD);
    wtrans_kernel<<<dim3(48, 12), blk, 0, stream>>>(W1 + (size_t)l * DD * DFF, W1T, DD, DFF);
    wtrans_kernel<<<dim3(12, 48), blk, 0, stream>>>(W2 + (size_t)l * DFF * DD, W2T, DFF, DD);

    ln_kernel<<<M, blk, 0, stream>>>(x, ln1g + l * DD, ln1b + l * DD, h);
    // fused QKV: Bt = [WqT;WkT;WvT] = [2304][768], bf16 out
    gemm_mfma<false, false, true><<<dim3(18 * 32), blk, 0, stream>>>(
        h, WqT, nullptr, nullptr, qkv, 3 * DD, DD, 32);
    fattn_kernel<<<dim3(TT / 64, HH, Bc), blk, 0, stream>>>(
        qkv, qkv + DD, qkv + 2 * DD, ob, 3 * DD);
    gemm_mfma<false, true, false><<<dim3(6 * 32), blk, 0, stream>>>(
        ob, WoT, bo + l * DD, x, x, DD, DD, 32);
    ln_kernel<<<M, blk, 0, stream>>>(x, ln2g + l * DD, ln2b + l * DD, h);
    gemm_mfma<true, false, true><<<dim3(24 * 32), blk, 0, stream>>>(
        h, W1T, b1 + l * DFF, nullptr, f1, DFF, DD, 32);
    gemm_mfma<false, true, false><<<dim3(6 * 32), blk, 0, stream>>>(
        f1, W2T, b2 + l * DD, x, x, DD, DFF, 32);
  }
  ln_kernel<<<M, blk, 0, stream>>>(x, lnfg, lnfb, h);
  wtrans_kernel<<<dim3(VV / 64, 12), blk, 0, stream>>>(hW, hWT, DD, VV);
  gemm_mfma<false, false, false><<<dim3(250 * 32), blk, 0, stream>>>(
      h, hWT, hb, nullptr, out, VV, DD, 32);
}